// Round 3
// baseline (905.990 us; speedup 1.0000x reference)
//
#include <hip/hip_runtime.h>
#include <cstdint>
#include <cstddef>

// ---------------------------------------------------------------------------
// NeuralODE, round 12: hybrid operand paths, order-robust prologue.
//   z' = f(z,t) = tanh([z,t]@W1 + b1) @ W2 + b2, Euler, 20 steps.
//   bs=1024, d=1024, hidden=2048. fp32 in/out; bf16 MFMA inside.
//
// R11 post-mortem: prologue {A0,S0,S1,A1} shared ONE asm-free region; the
// machine scheduler may emit those 12 VMEM ops in any order, so WAITV(6)
// "drain oldest 6" did not necessarily drain S0 before compute(0) ds_reads
// -> NaN. Compiler only protects register-dest loads (A-frags); the
// global_load_lds -> ds_read dependency is hand-ledger-only.
//
// Fix: STEP(0) drains vmcnt(0) (one-time, ~free), making the prologue
// correct under ANY issue order; SEP() asm splits the prologue region
// anyway. Steady state is region-aligned and order-robust:
//   region R(t) = [BARRIER(t) .. WAITV(t+1)] holds exactly S(t+2)+A(t+2)=6
//   ops; WAITV(6) at STEP(t+1) drains exactly the previous region ⊇ S(t+1).
// Per-iter issue: [A(i+1) x4][WAITV(6)][BAR][stage(i+2) x2][compute(i)].
// Tail: i=14 WAITV(6) drains S14+A14; i=15 WAITV(0).
// B via LDS (3 bufs, ONE barrier/tile), A direct global->regs (L1/L2-
// resident, 4-way wave reuse). Geometry unchanged:
//   gemm1: 64x128 block, 512 thr (2m x 4n waves of 32x32), grid 256
//   gemm2: 64x64 block K-split-2, 512 thr (2k x 2m x 2n) + LDS f32 reduce
// 2D XCD patch swizzle keeps per-XCD working set inside its L2.
// ---------------------------------------------------------------------------

typedef __bf16 bf16x8 __attribute__((ext_vector_type(8)));
typedef float f32x4 __attribute__((ext_vector_type(4)));

#define WAITV(N) asm volatile("s_waitcnt vmcnt(" #N ") lgkmcnt(0)" ::: "memory")
#define BARRIER() asm volatile("s_barrier" ::: "memory")
#define SEP() asm volatile("" ::: "memory")
#define MFMA(a, b, c) __builtin_amdgcn_mfma_f32_16x16x32_bf16(a, b, c, 0, 0, 0)

__device__ __forceinline__ unsigned short f2bf(float f) {
  union { float f; unsigned u; } v; v.f = f;
  unsigned r = v.u + 0x7fffu + ((v.u >> 16) & 1u);   // RNE
  return (unsigned short)(r >> 16);
}

// fast tanh: 1 - 2/(1+2^(2*log2e*x)); exact at +/-inf
__device__ __forceinline__ float fast_tanh(float x) {
  float e = __builtin_amdgcn_exp2f(x * 2.8853900817779268f);
  return 1.0f - 2.0f * __builtin_amdgcn_rcpf(1.0f + e);
}

// ---------------- prep: tiled transpose fp32 -> bf16 (out[cols][rows]) ------
__global__ void transpose_to_bf16(const float* __restrict__ in,
                                  unsigned short* __restrict__ out,
                                  int rows, int cols) {
  __shared__ float tile[32][33];
  int c0 = blockIdx.x * 32, r0 = blockIdx.y * 32;
  int tx = threadIdx.x, ty = threadIdx.y;
#pragma unroll
  for (int j = 0; j < 32; j += 8)
    tile[ty + j][tx] = in[(size_t)(r0 + ty + j) * cols + (c0 + tx)];
  __syncthreads();
#pragma unroll
  for (int j = 0; j < 32; j += 8)
    out[(size_t)(c0 + ty + j) * rows + (r0 + tx)] = f2bf(tile[tx][ty + j]);
}

// ---------------- prep: z copies + last W1 row ------------------------------
__global__ void prep_misc(const float* __restrict__ z0,
                          float* __restrict__ zf,
                          unsigned short* __restrict__ zbf,
                          const float* __restrict__ W1,
                          float* __restrict__ w1l, int n, int nl) {
  int i = blockIdx.x * blockDim.x + threadIdx.x;
  if (i < n) { float v = z0[i]; zf[i] = v; zbf[i] = f2bf(v); }
  if (i < nl) { w1l[i] = W1[(size_t)1024 * 2048 + i]; }
}

// stage 64 rows x 64 bf16 (8 KB) with 512 threads via global_load_lds,
// XOR-swizzled 16B chunks: row r slot s holds logical chunk s^(r&7).
__device__ __forceinline__ void stage64(const unsigned short* __restrict__ g,
                                        size_t ld, int row0, int k0,
                                        unsigned short* lp, int tid) {
  int r = tid >> 3;
  int c = (tid & 7) ^ (r & 7);
  __builtin_amdgcn_global_load_lds(
      (const __attribute__((address_space(1))) void*)(
          g + (size_t)(row0 + r) * ld + k0 + c * 8),
      (__attribute__((address_space(3))) void*)(lp + tid * 8), 16, 0, 0);
}

__device__ __forceinline__ bf16x8 frag_ld(const unsigned short* lp, int row,
                                          int chunk_logical, int x) {
  return *(const bf16x8*)(lp + row * 64 + ((chunk_logical ^ x) << 3));
}

// ---------------- GEMM1: H = tanh(Zb @ W1T^T + b1 + t*w1l) ------------------
// 64x128 block, K=1024 (16 BK=64 tiles), 512 thr = 8 waves (2m x 4n, 32x32).
// B (W1T) via LDS, 3 bufs x 8192 shorts; A (Zb) global->regs, dbuf. grid 256.
__global__ __launch_bounds__(512, 1) void gemm1_kernel(
    const unsigned short* __restrict__ Zb,    // [1024][1024] bf16
    const unsigned short* __restrict__ W1T,   // [2048][1024] bf16 (N-major)
    unsigned short* __restrict__ H,           // [1024][2048] bf16
    const float* __restrict__ b1, const float* __restrict__ w1l, float tval) {
  __shared__ __align__(16) unsigned short lds[24576];  // 48 KB, 3 x 16 KB
  const int tid = threadIdx.x;
  const int lane = tid & 63, wid = tid >> 6;
  const int l15 = lane & 15, q = lane >> 4, x = l15 & 7;
  const int bid = blockIdx.x;
  const int xcd = bid & 7, loc = bid >> 3;
  const int mt = (loc & 3) | ((xcd & 3) << 2);    // 16 m-tiles, 4/XCD
  const int nt = (loc >> 2) | ((xcd >> 2) << 3);  // 16 n-tiles, 8/XCD
  const int m0 = mt * 64, n0 = nt * 128;

  unsigned short* const buf0 = lds;
  unsigned short* const buf1 = lds + 8192;
  unsigned short* const buf2 = lds + 16384;

  f32x4 acc00 = {}, acc01 = {}, acc10 = {}, acc11 = {};
  bf16x8 a0A, a1A, a2A, a3A, a0B, a1B, a2B, a3B;

  // A fragment base: rows m0+(wid&1)*32 + {0,16} + l15, cols t*64 + kk*32 + q*8
  const unsigned short* const Abase =
      Zb + (size_t)(m0 + (wid & 1) * 32 + l15) * 1024 + q * 8;

  auto stage_tile = [&](int t, unsigned short* p) {   // 2 loads/thread (B only)
    int k = t * 64;
    stage64(W1T, 1024, n0, k, p, tid);
    stage64(W1T, 1024, n0 + 64, k, p + 4096, tid);
  };

#define LOADA(t, s)                                         \
  do {                                                      \
    const unsigned short* _p = Abase + (t) * 64;            \
    a0##s = *(const bf16x8*)(_p);                           \
    a1##s = *(const bf16x8*)(_p + 32);                      \
    a2##s = *(const bf16x8*)(_p + 16 * 1024);               \
    a3##s = *(const bf16x8*)(_p + 16 * 1024 + 32);          \
  } while (0)

#define COMPUTE(p, s)                                       \
  do {                                                      \
    const unsigned short* _B = (p) + (wid >> 1) * 2048;     \
    bf16x8 _b0 = frag_ld(_B, l15, q, x);                    \
    bf16x8 _b1 = frag_ld(_B, 16 + l15, q, x);               \
    bf16x8 _b2 = frag_ld(_B, l15, 4 + q, x);                \
    bf16x8 _b3 = frag_ld(_B, 16 + l15, 4 + q, x);           \
    acc00 = MFMA(a0##s, _b0, acc00);                        \
    acc01 = MFMA(a0##s, _b1, acc01);                        \
    acc10 = MFMA(a2##s, _b0, acc10);                        \
    acc11 = MFMA(a2##s, _b1, acc11);                        \
    acc00 = MFMA(a1##s, _b2, acc00);                        \
    acc01 = MFMA(a1##s, _b3, acc01);                        \
    acc10 = MFMA(a3##s, _b2, acc10);                        \
    acc11 = MFMA(a3##s, _b3, acc11);                        \
  } while (0)

#define STEP(t, sc, sn, pc, pn, W) \
  LOADA((t) + 1, sn);              \
  WAITV(W);                        \
  BARRIER();                       \
  stage_tile((t) + 2, pn);         \
  COMPUTE(pc, sc)

  LOADA(0, A);            // region P0: A0(4)+S0(2)
  stage_tile(0, buf0);
  SEP();
  stage_tile(1, buf1);    // region P1: S1(2)+A1(4)

  STEP(0, A, B, buf0, buf2, 0);   // full drain: prologue-order-proof
  STEP(1, B, A, buf1, buf0, 6);
  STEP(2, A, B, buf2, buf1, 6);
  STEP(3, B, A, buf0, buf2, 6);
  STEP(4, A, B, buf1, buf0, 6);
  STEP(5, B, A, buf2, buf1, 6);
  STEP(6, A, B, buf0, buf2, 6);
  STEP(7, B, A, buf1, buf0, 6);
  STEP(8, A, B, buf2, buf1, 6);
  STEP(9, B, A, buf0, buf2, 6);
  STEP(10, A, B, buf1, buf0, 6);
  STEP(11, B, A, buf2, buf1, 6);
  STEP(12, A, B, buf0, buf2, 6);
  STEP(13, B, A, buf1, buf0, 6);
  // t=14: outstanding = [S14,A14] + [S15,A15(4 after LOADA)] = 12; drain 6.
  LOADA(15, B);
  WAITV(6);
  BARRIER();
  COMPUTE(buf2, A);
  // t=15: drain S15+A15.
  WAITV(0);
  BARRIER();
  COMPUTE(buf0, B);
#undef LOADA
#undef COMPUTE
#undef STEP

  {
    const int colb = n0 + (wid >> 1) * 32 + l15;
    const int rowb = m0 + (wid & 1) * 32 + q * 4;
    const float bia0 = b1[colb] + tval * w1l[colb];
    const float bia1 = b1[colb + 16] + tval * w1l[colb + 16];
#pragma unroll
    for (int r = 0; r < 4; ++r) {
      H[(size_t)(rowb + r) * 2048 + colb]        = f2bf(fast_tanh(acc00[r] + bia0));
      H[(size_t)(rowb + r) * 2048 + colb + 16]   = f2bf(fast_tanh(acc01[r] + bia1));
      H[(size_t)(rowb + 16 + r) * 2048 + colb]      = f2bf(fast_tanh(acc10[r] + bia0));
      H[(size_t)(rowb + 16 + r) * 2048 + colb + 16] = f2bf(fast_tanh(acc11[r] + bia1));
    }
  }
}

// ---------------- GEMM2: z' = zf + h*(H @ W2T^T + b2) -----------------------
// 64x64 block, K=2048 as 16 super-tiles (64 in each K-half), 512 thr = 8
// waves (kh = wid>>2, mh = (wid>>1)&1, nh = wid&1; each 32x32). B (W2T) via
// LDS 3 bufs x 8192 shorts; A (Hb) global->regs dbuf. LDS f32 reduce kh1->kh0.
__global__ __launch_bounds__(512, 1) void gemm2_kernel(
    const unsigned short* __restrict__ Hb,    // [1024][2048] bf16
    const unsigned short* __restrict__ W2T,   // [1024][2048] bf16 (N-major)
    const float* __restrict__ b2,
    const float* __restrict__ zf,
    float* __restrict__ outf,                 // zf, or d_out on last step
    unsigned short* __restrict__ zbf,
    float h) {
  __shared__ __align__(16) unsigned short lds[24576];  // 48 KB, 3 x 16 KB
  const int tid = threadIdx.x;
  const int lane = tid & 63, wid = tid >> 6;
  const int l15 = lane & 15, q = lane >> 4, x = l15 & 7;
  const int kh = wid >> 2, mh = (wid >> 1) & 1, nh = wid & 1;
  const int bid = blockIdx.x;
  const int xcd = bid & 7, loc = bid >> 3;
  const int mt = (loc & 3) | ((xcd & 3) << 2);    // 16 m-tiles, 4/XCD
  const int nt = (loc >> 2) | ((xcd >> 2) << 3);  // 16 n-tiles, 8/XCD
  const int m0 = mt * 64, n0 = nt * 64;

  unsigned short* const buf0 = lds;
  unsigned short* const buf1 = lds + 8192;
  unsigned short* const buf2 = lds + 16384;

  f32x4 acc00 = {}, acc01 = {}, acc10 = {}, acc11 = {};
  bf16x8 a0A, a1A, a2A, a3A, a0B, a1B, a2B, a3B;

  const unsigned short* const Abase =
      Hb + (size_t)(m0 + mh * 32 + l15) * 2048 + kh * 1024 + q * 8;

  auto stage_tile = [&](int t, unsigned short* p) {   // 2 loads/thread (B only)
    int k = t * 64;
    stage64(W2T, 2048, n0, k, p, tid);                // B kh=0
    stage64(W2T, 2048, n0, k + 1024, p + 4096, tid);  // B kh=1
  };

#define LOADA(t, s)                                         \
  do {                                                      \
    const unsigned short* _p = Abase + (t) * 64;            \
    a0##s = *(const bf16x8*)(_p);                           \
    a1##s = *(const bf16x8*)(_p + 32);                      \
    a2##s = *(const bf16x8*)(_p + 16 * 2048);               \
    a3##s = *(const bf16x8*)(_p + 16 * 2048 + 32);          \
  } while (0)

#define COMPUTE(p, s)                                       \
  do {                                                      \
    const unsigned short* _B = (p) + kh * 4096 + nh * 2048; \
    bf16x8 _b0 = frag_ld(_B, l15, q, x);                    \
    bf16x8 _b1 = frag_ld(_B, 16 + l15, q, x);               \
    bf16x8 _b2 = frag_ld(_B, l15, 4 + q, x);                \
    bf16x8 _b3 = frag_ld(_B, 16 + l15, 4 + q, x);           \
    acc00 = MFMA(a0##s, _b0, acc00);                        \
    acc01 = MFMA(a0##s, _b1, acc01);                        \
    acc10 = MFMA(a2##s, _b0, acc10);                        \
    acc11 = MFMA(a2##s, _b1, acc11);                        \
    acc00 = MFMA(a1##s, _b2, acc00);                        \
    acc01 = MFMA(a1##s, _b3, acc01);                        \
    acc10 = MFMA(a3##s, _b2, acc10);                        \
    acc11 = MFMA(a3##s, _b3, acc11);                        \
  } while (0)

#define STEP(t, sc, sn, pc, pn, W) \
  LOADA((t) + 1, sn);              \
  WAITV(W);                        \
  BARRIER();                       \
  stage_tile((t) + 2, pn);         \
  COMPUTE(pc, sc)

  LOADA(0, A);
  stage_tile(0, buf0);
  SEP();
  stage_tile(1, buf1);

  STEP(0, A, B, buf0, buf2, 0);   // full drain: prologue-order-proof
  STEP(1, B, A, buf1, buf0, 6);
  STEP(2, A, B, buf2, buf1, 6);
  STEP(3, B, A, buf0, buf2, 6);
  STEP(4, A, B, buf1, buf0, 6);
  STEP(5, B, A, buf2, buf1, 6);
  STEP(6, A, B, buf0, buf2, 6);
  STEP(7, B, A, buf1, buf0, 6);
  STEP(8, A, B, buf2, buf1, 6);
  STEP(9, B, A, buf0, buf2, 6);
  STEP(10, A, B, buf1, buf0, 6);
  STEP(11, B, A, buf2, buf1, 6);
  STEP(12, A, B, buf0, buf2, 6);
  STEP(13, B, A, buf1, buf0, 6);
  LOADA(15, B);
  WAITV(6);
  BARRIER();
  COMPUTE(buf2, A);
  WAITV(0);
  BARRIER();
  COMPUTE(buf0, B);
#undef LOADA
#undef COMPUTE
#undef STEP

  // K-split reduce: kh=1 waves publish to LDS (f32, stride 33), kh=0 add.
  __syncthreads();
  float* red = (float*)lds;
  const int region = (mh * 2 + nh) * 1056;   // 32*33 floats per (mh,nh)
  const int rl = q * 4;
  if (kh == 1) {
#pragma unroll
    for (int r = 0; r < 4; ++r) {
      red[region + (rl + r) * 33 + l15]           = acc00[r];
      red[region + (rl + r) * 33 + 16 + l15]      = acc01[r];
      red[region + (16 + rl + r) * 33 + l15]      = acc10[r];
      red[region + (16 + rl + r) * 33 + 16 + l15] = acc11[r];
    }
  }
  __syncthreads();
  if (kh == 0) {
    const int colb = n0 + nh * 32 + l15;
    const float bb0 = b2[colb], bb1 = b2[colb + 16];
#pragma unroll
    for (int r = 0; r < 4; ++r) {
      float s00 = acc00[r] + red[region + (rl + r) * 33 + l15];
      size_t g00 = (size_t)(m0 + mh * 32 + rl + r) * 1024 + colb;
      float z00 = zf[g00] + h * (s00 + bb0);
      outf[g00] = z00; zbf[g00] = f2bf(z00);

      float s01 = acc01[r] + red[region + (rl + r) * 33 + 16 + l15];
      size_t g01 = g00 + 16;
      float z01 = zf[g01] + h * (s01 + bb1);
      outf[g01] = z01; zbf[g01] = f2bf(z01);

      float s10 = acc10[r] + red[region + (16 + rl + r) * 33 + l15];
      size_t g10 = (size_t)(m0 + mh * 32 + 16 + rl + r) * 1024 + colb;
      float z10 = zf[g10] + h * (s10 + bb0);
      outf[g10] = z10; zbf[g10] = f2bf(z10);

      float s11 = acc11[r] + red[region + (16 + rl + r) * 33 + 16 + l15];
      size_t g11 = g10 + 16;
      float z11 = zf[g11] + h * (s11 + bb1);
      outf[g11] = z11; zbf[g11] = f2bf(z11);
    }
  }
}

// ---------------------------------------------------------------------------
extern "C" void kernel_launch(void* const* d_in, const int* in_sizes, int n_in,
                              void* d_out, int out_size, void* d_ws,
                              size_t ws_size, hipStream_t stream) {
  const float* z0 = (const float*)d_in[0];
  // d_in[1] = t (linspace 0..1, 5) — reproduced exactly in f32 arithmetic
  const float* W1 = (const float*)d_in[2];
  const float* b1 = (const float*)d_in[3];
  const float* W2 = (const float*)d_in[4];
  const float* b2 = (const float*)d_in[5];
  float* out = (float*)d_out;

  char* ws = (char*)d_ws;
  unsigned short* W1T = (unsigned short*)(ws + 0);              // 4 MB
  unsigned short* W2T = (unsigned short*)(ws + (4u << 20));     // 4 MB
  unsigned short* zbf = (unsigned short*)(ws + (8u << 20));     // 2 MB
  unsigned short* Hbf = (unsigned short*)(ws + (10u << 20));    // 4 MB
  float* zf = (float*)(ws + (14u << 20));                       // 4 MB
  float* w1l = (float*)(ws + (18u << 20));                      // 8 KB

  transpose_to_bf16<<<dim3(64, 32), dim3(32, 8), 0, stream>>>(W1, W1T, 1024, 2048);
  transpose_to_bf16<<<dim3(32, 64), dim3(32, 8), 0, stream>>>(W2, W2T, 2048, 1024);
  prep_misc<<<4096, 256, 0, stream>>>(z0, zf, zbf, W1, w1l, 1024 * 1024, 2048);

  const float h = 0.05f;  // (t[i+1]-t[i])/5 in f32 == 0.05f for all segments
  for (int seg = 0; seg < 4; ++seg) {
    float tcur = 0.25f * (float)seg;  // t[seg] (exact in f32)
    for (int j = 0; j < 5; ++j) {
      gemm1_kernel<<<256, 512, 0, stream>>>(zbf, W1T, Hbf, b1, w1l, tcur);
      bool last = (seg == 3 && j == 4);
      float* outf = last ? out : zf;
      gemm2_kernel<<<256, 512, 0, stream>>>(Hbf, W2T, b2, zf, outf, zbf, h);
      tcur += h;  // matches reference's sequential f32 accumulation
    }
  }
}

// Round 4
// 432.251 us; speedup vs baseline: 2.0960x; 2.0960x over previous
//
#include <hip/hip_runtime.h>
#include <cstdint>
#include <cstddef>

// ---------------------------------------------------------------------------
// NeuralODE, round 13: R9 staging + proven 3-buffer single-barrier pipeline.
//   z' = f(z,t) = tanh([z,t]@W1 + b1) @ W2 + b2, Euler, 20 steps.
//   bs=1024, d=1024, hidden=2048. fp32 in/out; bf16 MFMA inside.
//
// R12 post-mortem: ledger correct (absmax exact), but direct-A per-wave
// global loads = 32 VMEM inst/tile/CU vs 3 staged (4-way redundancy, 16
// scattered lines each) -> L1/TA path serialization -> 2x regression.
// Staging deduplicates; A goes back through global_load_lds.
//
// R13 = R9 tile geometry + staging, with ONE barrier per tile via 3 LDS
// buffers (R12's proven rotation):
//   STEP(t): WAITV(S) [drain own S(t); per-wave vmcnt BEFORE barrier]
//            BARRIER  [-> all waves' S(t) resident; all waves' compute(t-1)
//                      ds_reads drained (lgkmcnt(0) in WAITV) -> buf free]
//            stage(t+2) into buf[(t+2)%3]  [= buf compute(t-1) just freed;
//                      issued BEFORE compute -> 2 compute phases of slack]
//            compute(t) on buf[t%3]
// Ledger (gemm1 S=3 loads, gemm2 S=4): steady outstanding at WAITV =
// S(t)+S(t+1) -> drain S(t). Prologue S0;SEP;S1 pins issue order. Tail:
// t=14 no stage; t=15 WAITV(0).
//   gemm1: 64x128 block, 512 thr (2m x 4n waves of 32x32), grid 256
//   gemm2: 64x64 block K-split-2, 512 thr (2k x 2m x 2n) + LDS f32 reduce
// 2D XCD patch swizzle keeps per-XCD working set inside its L2.
// ---------------------------------------------------------------------------

typedef __bf16 bf16x8 __attribute__((ext_vector_type(8)));
typedef float f32x4 __attribute__((ext_vector_type(4)));

#define WAITV(N) asm volatile("s_waitcnt vmcnt(" #N ") lgkmcnt(0)" ::: "memory")
#define BARRIER() asm volatile("s_barrier" ::: "memory")
#define SEP() asm volatile("" ::: "memory")

__device__ __forceinline__ unsigned short f2bf(float f) {
  union { float f; unsigned u; } v; v.f = f;
  unsigned r = v.u + 0x7fffu + ((v.u >> 16) & 1u);   // RNE
  return (unsigned short)(r >> 16);
}

// fast tanh: 1 - 2/(1+2^(2*log2e*x)); exact at +/-inf
__device__ __forceinline__ float fast_tanh(float x) {
  float e = __builtin_amdgcn_exp2f(x * 2.8853900817779268f);
  return 1.0f - 2.0f * __builtin_amdgcn_rcpf(1.0f + e);
}

// ---------------- prep: tiled transpose fp32 -> bf16 (out[cols][rows]) ------
__global__ void transpose_to_bf16(const float* __restrict__ in,
                                  unsigned short* __restrict__ out,
                                  int rows, int cols) {
  __shared__ float tile[32][33];
  int c0 = blockIdx.x * 32, r0 = blockIdx.y * 32;
  int tx = threadIdx.x, ty = threadIdx.y;
#pragma unroll
  for (int j = 0; j < 32; j += 8)
    tile[ty + j][tx] = in[(size_t)(r0 + ty + j) * cols + (c0 + tx)];
  __syncthreads();
#pragma unroll
  for (int j = 0; j < 32; j += 8)
    out[(size_t)(c0 + ty + j) * rows + (r0 + tx)] = f2bf(tile[tx][ty + j]);
}

// ---------------- prep: z copies + last W1 row ------------------------------
__global__ void prep_misc(const float* __restrict__ z0,
                          float* __restrict__ zf,
                          unsigned short* __restrict__ zbf,
                          const float* __restrict__ W1,
                          float* __restrict__ w1l, int n, int nl) {
  int i = blockIdx.x * blockDim.x + threadIdx.x;
  if (i < n) { float v = z0[i]; zf[i] = v; zbf[i] = f2bf(v); }
  if (i < nl) { w1l[i] = W1[(size_t)1024 * 2048 + i]; }
}

// stage 64 rows x 64 bf16 (8 KB) with 512 threads via global_load_lds,
// XOR-swizzled 16B chunks: row r slot s holds logical chunk s^(r&7).
__device__ __forceinline__ void stage64(const unsigned short* __restrict__ g,
                                        size_t ld, int row0, int k0,
                                        unsigned short* lp, int tid) {
  int r = tid >> 3;
  int c = (tid & 7) ^ (r & 7);
  __builtin_amdgcn_global_load_lds(
      (const __attribute__((address_space(1))) void*)(
          g + (size_t)(row0 + r) * ld + k0 + c * 8),
      (__attribute__((address_space(3))) void*)(lp + tid * 8), 16, 0, 0);
}

__device__ __forceinline__ bf16x8 frag_ld(const unsigned short* lp, int row,
                                          int chunk_logical, int x) {
  return *(const bf16x8*)(lp + row * 64 + ((chunk_logical ^ x) << 3));
}

// ---------------- GEMM1: H = tanh(Zb @ W1T^T + b1 + t*w1l) ------------------
// 64x128 block, K=1024 (16 BK=64 tiles), 512 thr = 8 waves (2m x 4n, 32x32),
// 3 LDS bufs x 12288 shorts (A 4096 + B 8192). grid 256 (1/CU).
__global__ __launch_bounds__(512, 1) void gemm1_kernel(
    const unsigned short* __restrict__ Zb,    // [1024][1024] bf16
    const unsigned short* __restrict__ W1T,   // [2048][1024] bf16 (N-major)
    unsigned short* __restrict__ H,           // [1024][2048] bf16
    const float* __restrict__ b1, const float* __restrict__ w1l, float tval) {
  __shared__ __align__(16) unsigned short lds[36864];  // 72 KB, 3 x 24 KB
  const int tid = threadIdx.x;
  const int lane = tid & 63, wid = tid >> 6;
  const int l15 = lane & 15, q = lane >> 4, x = l15 & 7;
  const int bid = blockIdx.x;
  const int xcd = bid & 7, loc = bid >> 3;
  const int mt = (loc & 3) | ((xcd & 3) << 2);    // 16 m-tiles, 4/XCD
  const int nt = (loc >> 2) | ((xcd >> 2) << 3);  // 16 n-tiles, 8/XCD
  const int m0 = mt * 64, n0 = nt * 128;

  unsigned short* const buf0 = lds;
  unsigned short* const buf1 = lds + 12288;
  unsigned short* const buf2 = lds + 24576;

  f32x4 acc[2][2] = {};

  auto stage_tile = [&](int t, unsigned short* p) {   // 3 loads/thread
    int k = t * 64;
    stage64(Zb, 1024, m0, k, p, tid);
    stage64(W1T, 1024, n0, k, p + 4096, tid);
    stage64(W1T, 1024, n0 + 64, k, p + 8192, tid);
  };
  auto compute = [&](const unsigned short* p) {
    const unsigned short* A = p + (wid & 1) * 2048;
    const unsigned short* B = p + 4096 + (wid >> 1) * 2048;
#pragma unroll
    for (int kk = 0; kk < 2; ++kk) {
      bf16x8 a[2], bb[2];
#pragma unroll
      for (int im = 0; im < 2; ++im)
        a[im] = frag_ld(A, im * 16 + l15, (kk << 2) + q, x);
#pragma unroll
      for (int jn = 0; jn < 2; ++jn)
        bb[jn] = frag_ld(B, jn * 16 + l15, (kk << 2) + q, x);
#pragma unroll
      for (int im = 0; im < 2; ++im)
#pragma unroll
        for (int jn = 0; jn < 2; ++jn)
          acc[im][jn] = __builtin_amdgcn_mfma_f32_16x16x32_bf16(
              a[im], bb[jn], acc[im][jn], 0, 0, 0);
    }
  };

#define STEP(t, pc, pn) \
  WAITV(3);             \
  BARRIER();            \
  stage_tile((t) + 2, pn); \
  compute(pc)

  stage_tile(0, buf0);   // S0 (3)
  SEP();                 // pin S0 before S1 so WAITV(3) drains exactly S0
  stage_tile(1, buf1);   // S1 (3)

  STEP(0, buf0, buf2);
  STEP(1, buf1, buf0);
  STEP(2, buf2, buf1);
  STEP(3, buf0, buf2);
  STEP(4, buf1, buf0);
  STEP(5, buf2, buf1);
  STEP(6, buf0, buf2);
  STEP(7, buf1, buf0);
  STEP(8, buf2, buf1);
  STEP(9, buf0, buf2);
  STEP(10, buf1, buf0);
  STEP(11, buf2, buf1);
  STEP(12, buf0, buf2);
  STEP(13, buf1, buf0);
  // t=14: outstanding S14+S15 = 6 -> drain S14; no stage.
  WAITV(3);
  BARRIER();
  compute(buf2);
  // t=15: drain S15.
  WAITV(0);
  BARRIER();
  compute(buf0);
#undef STEP

#pragma unroll
  for (int jn = 0; jn < 2; ++jn) {
    int col = n0 + (wid >> 1) * 32 + jn * 16 + l15;
    float bb = b1[col] + tval * w1l[col];
#pragma unroll
    for (int im = 0; im < 2; ++im) {
      int rowb = m0 + (wid & 1) * 32 + im * 16 + q * 4;
#pragma unroll
      for (int r = 0; r < 4; ++r)
        H[(size_t)(rowb + r) * 2048 + col] =
            f2bf(fast_tanh(acc[im][jn][r] + bb));
    }
  }
}

// ---------------- GEMM2: z' = zf + h*(H @ W2T^T + b2) -----------------------
// 64x64 block, K=2048 as 16 super-tiles (64 in each K-half), 512 thr = 8
// waves (kh = wid>>2, mh = (wid>>1)&1, nh = wid&1; each 32x32), 3 LDS bufs x
// 16384 shorts (A0,A1,B0,B1 of 4096). LDS f32 reduce of kh=1 into kh=0.
__global__ __launch_bounds__(512, 1) void gemm2_kernel(
    const unsigned short* __restrict__ Hb,    // [1024][2048] bf16
    const unsigned short* __restrict__ W2T,   // [1024][2048] bf16 (N-major)
    const float* __restrict__ b2,
    const float* __restrict__ zf,
    float* __restrict__ outf,                 // zf, or d_out on last step
    unsigned short* __restrict__ zbf,
    float h) {
  __shared__ __align__(16) unsigned short lds[49152];  // 96 KB, 3 x 32 KB
  const int tid = threadIdx.x;
  const int lane = tid & 63, wid = tid >> 6;
  const int l15 = lane & 15, q = lane >> 4, x = l15 & 7;
  const int kh = wid >> 2, mh = (wid >> 1) & 1, nh = wid & 1;
  const int bid = blockIdx.x;
  const int xcd = bid & 7, loc = bid >> 3;
  const int mt = (loc & 3) | ((xcd & 3) << 2);    // 16 m-tiles, 4/XCD
  const int nt = (loc >> 2) | ((xcd >> 2) << 3);  // 16 n-tiles, 8/XCD
  const int m0 = mt * 64, n0 = nt * 64;

  unsigned short* const buf0 = lds;
  unsigned short* const buf1 = lds + 16384;
  unsigned short* const buf2 = lds + 32768;

  f32x4 acc[2][2] = {};

  auto stage_tile = [&](int t, unsigned short* p) {   // 4 loads/thread
    int k = t * 64;
    stage64(Hb, 2048, m0, k, p, tid);                   // A kh=0
    stage64(Hb, 2048, m0, k + 1024, p + 4096, tid);     // A kh=1
    stage64(W2T, 2048, n0, k, p + 8192, tid);           // B kh=0
    stage64(W2T, 2048, n0, k + 1024, p + 12288, tid);   // B kh=1
  };
  auto compute = [&](const unsigned short* p) {
    const unsigned short* A = p + kh * 4096 + mh * 2048;
    const unsigned short* B = p + 8192 + kh * 4096 + nh * 2048;
#pragma unroll
    for (int kk = 0; kk < 2; ++kk) {
      bf16x8 a[2], bb[2];
#pragma unroll
      for (int im = 0; im < 2; ++im)
        a[im] = frag_ld(A, im * 16 + l15, (kk << 2) + q, x);
#pragma unroll
      for (int jn = 0; jn < 2; ++jn)
        bb[jn] = frag_ld(B, jn * 16 + l15, (kk << 2) + q, x);
#pragma unroll
      for (int im = 0; im < 2; ++im)
#pragma unroll
        for (int jn = 0; jn < 2; ++jn)
          acc[im][jn] = __builtin_amdgcn_mfma_f32_16x16x32_bf16(
              a[im], bb[jn], acc[im][jn], 0, 0, 0);
    }
  };

#define STEP(t, pc, pn) \
  WAITV(4);             \
  BARRIER();            \
  stage_tile((t) + 2, pn); \
  compute(pc)

  stage_tile(0, buf0);   // S0 (4)
  SEP();                 // pin S0 before S1
  stage_tile(1, buf1);   // S1 (4)

  STEP(0, buf0, buf2);
  STEP(1, buf1, buf0);
  STEP(2, buf2, buf1);
  STEP(3, buf0, buf2);
  STEP(4, buf1, buf0);
  STEP(5, buf2, buf1);
  STEP(6, buf0, buf2);
  STEP(7, buf1, buf0);
  STEP(8, buf2, buf1);
  STEP(9, buf0, buf2);
  STEP(10, buf1, buf0);
  STEP(11, buf2, buf1);
  STEP(12, buf0, buf2);
  STEP(13, buf1, buf0);
  WAITV(4);
  BARRIER();
  compute(buf2);
  WAITV(0);
  BARRIER();
  compute(buf0);
#undef STEP

  // K-split reduce: kh=1 waves publish to LDS (f32, stride 33), kh=0 add.
  __syncthreads();
  float* red = (float*)lds;
  const int region = (mh * 2 + nh) * 1056;   // 32*33 floats per (mh,nh)
  if (kh == 1) {
#pragma unroll
    for (int im = 0; im < 2; ++im)
#pragma unroll
      for (int jn = 0; jn < 2; ++jn) {
        int c = jn * 16 + l15;
#pragma unroll
        for (int r = 0; r < 4; ++r)
          red[region + (im * 16 + q * 4 + r) * 33 + c] = acc[im][jn][r];
      }
  }
  __syncthreads();
  if (kh == 0) {
#pragma unroll
    for (int jn = 0; jn < 2; ++jn) {
      int coll = nh * 32 + jn * 16 + l15;
      int col = n0 + coll;
      float bb = b2[col];
#pragma unroll
      for (int im = 0; im < 2; ++im) {
        int rowl = im * 16 + q * 4;
#pragma unroll
        for (int r = 0; r < 4; ++r) {
          float s = acc[im][jn][r] +
                    red[region + (rowl + r) * 33 + jn * 16 + l15];
          size_t gidx = (size_t)(m0 + mh * 32 + rowl + r) * 1024 + col;
          float zv = zf[gidx] + h * (s + bb);
          outf[gidx] = zv;
          zbf[gidx] = f2bf(zv);
        }
      }
    }
  }
}

// ---------------------------------------------------------------------------
extern "C" void kernel_launch(void* const* d_in, const int* in_sizes, int n_in,
                              void* d_out, int out_size, void* d_ws,
                              size_t ws_size, hipStream_t stream) {
  const float* z0 = (const float*)d_in[0];
  // d_in[1] = t (linspace 0..1, 5) — reproduced exactly in f32 arithmetic
  const float* W1 = (const float*)d_in[2];
  const float* b1 = (const float*)d_in[3];
  const float* W2 = (const float*)d_in[4];
  const float* b2 = (const float*)d_in[5];
  float* out = (float*)d_out;

  char* ws = (char*)d_ws;
  unsigned short* W1T = (unsigned short*)(ws + 0);              // 4 MB
  unsigned short* W2T = (unsigned short*)(ws + (4u << 20));     // 4 MB
  unsigned short* zbf = (unsigned short*)(ws + (8u << 20));     // 2 MB
  unsigned short* Hbf = (unsigned short*)(ws + (10u << 20));    // 4 MB
  float* zf = (float*)(ws + (14u << 20));                       // 4 MB
  float* w1l = (float*)(ws + (18u << 20));                      // 8 KB

  transpose_to_bf16<<<dim3(64, 32), dim3(32, 8), 0, stream>>>(W1, W1T, 1024, 2048);
  transpose_to_bf16<<<dim3(32, 64), dim3(32, 8), 0, stream>>>(W2, W2T, 2048, 1024);
  prep_misc<<<4096, 256, 0, stream>>>(z0, zf, zbf, W1, w1l, 1024 * 1024, 2048);

  const float h = 0.05f;  // (t[i+1]-t[i])/5 in f32 == 0.05f for all segments
  for (int seg = 0; seg < 4; ++seg) {
    float tcur = 0.25f * (float)seg;  // t[seg] (exact in f32)
    for (int j = 0; j < 5; ++j) {
      gemm1_kernel<<<256, 512, 0, stream>>>(zbf, W1T, Hbf, b1, w1l, tcur);
      bool last = (seg == 3 && j == 4);
      float* outf = last ? out : zf;
      gemm2_kernel<<<256, 512, 0, stream>>>(Hbf, W2T, b2, zf, outf, zbf, h);
      tcur += h;  // matches reference's sequential f32 accumulation
    }
  }
}